// Round 1
// baseline (23828.468 us; speedup 1.0000x reference)
//
#include <hip/hip_runtime.h>

#define DEV __device__ __forceinline__

namespace {
constexpr int Bc = 32;
constexpr int Tc = 256;
constexpr int Dc = 512;
constexpr int Sc = 2048;
constexpr int NBLK = 256;          // persistent kernel blocks (<= #CUs, co-resident)
constexpr int NW   = 128;          // writer blocks
constexpr int ROWS = Sc / NW;      // 16 memory rows per W block

// workspace layout (float offsets)
constexpr size_t OFF_KN  = 0;                                   // [T][B][D] normalized k
constexpr size_t OFF_E   = OFF_KN  + (size_t)Tc * Bc * Dc;      // [T][B][D] sigmoid(erase)
constexpr size_t OFF_A   = OFF_E   + (size_t)Tc * Bc * Dc;      // [T][B][D] add
constexpr size_t OFF_MEM = OFF_A   + (size_t)Tc * Bc * Dc;      // [2][S][D] memory ping-pong
constexpr size_t OFF_EW  = OFF_MEM + (size_t)2 * Sc * Dc;       // [2][S][B] exp(sim)
constexpr size_t OFF_RP  = OFF_EW  + (size_t)2 * Sc * Bc;       // [2][16][B][D] read partials
constexpr size_t OFF_DEN = OFF_RP  + (size_t)2 * 16 * Bc * Dc;  // [T][B] softmax denominators
constexpr size_t OFF_CNT = OFF_DEN + (size_t)Tc * Bc;           // barrier counter (u32)
}

DEV float sigm(float x) { return 1.0f / (1.0f + __expf(-x)); }

// ---------------------------------------------------------------------------
// K1: C[r][j] = sum_d A[r][d] * W[j][d] + bias[j], for 4 weight matrices.
// A = controller_seq flattened [B*T][D] (row r = b*T + t).
// mat 0 -> raw k into ws[KN] (normalized by K2); mat 1 -> sigmoid into ws[E];
// mat 2 -> raw into ws[A]; mat 3 -> sigmoid(g) into d_out (temp storage).
// ---------------------------------------------------------------------------
__global__ __launch_bounds__(256) void k_gemm(
    const float* __restrict__ A,
    const float* __restrict__ Wk, const float* __restrict__ bk,
    const float* __restrict__ We, const float* __restrict__ be,
    const float* __restrict__ Ww, const float* __restrict__ bw,
    const float* __restrict__ Wg, const float* __restrict__ bg,
    float* __restrict__ ws, float* __restrict__ gout)
{
  __shared__ float As[32][68];
  __shared__ float Bs[32][68];

  const int bid = blockIdx.x;
  const int mat = bid >> 10;            // 1024 blocks per matrix
  const int rem = bid & 1023;
  const int rt = rem >> 3, jt = rem & 7;
  const int rbase = rt * 64, jbase = jt * 64;

  const float* Wm; const float* bm;
  if      (mat == 0) { Wm = Wk; bm = bk; }
  else if (mat == 1) { Wm = We; bm = be; }
  else if (mat == 2) { Wm = Ww; bm = bw; }
  else               { Wm = Wg; bm = bg; }

  const int tid = threadIdx.x;
  const int lr = tid >> 2;              // 0..63
  const int lk = (tid & 3) * 8;         // 0,8,16,24
  const int ty = tid >> 4, tx = tid & 15;

  float acc[4][4] = {};

  for (int k0 = 0; k0 < Dc; k0 += 32) {
    const float4 a0 = *(const float4*)&A [(size_t)(rbase + lr) * Dc + k0 + lk];
    const float4 a1 = *(const float4*)&A [(size_t)(rbase + lr) * Dc + k0 + lk + 4];
    const float4 b0 = *(const float4*)&Wm[(size_t)(jbase + lr) * Dc + k0 + lk];
    const float4 b1 = *(const float4*)&Wm[(size_t)(jbase + lr) * Dc + k0 + lk + 4];
    __syncthreads();
    As[lk + 0][lr] = a0.x; As[lk + 1][lr] = a0.y; As[lk + 2][lr] = a0.z; As[lk + 3][lr] = a0.w;
    As[lk + 4][lr] = a1.x; As[lk + 5][lr] = a1.y; As[lk + 6][lr] = a1.z; As[lk + 7][lr] = a1.w;
    Bs[lk + 0][lr] = b0.x; Bs[lk + 1][lr] = b0.y; Bs[lk + 2][lr] = b0.z; Bs[lk + 3][lr] = b0.w;
    Bs[lk + 4][lr] = b1.x; Bs[lk + 5][lr] = b1.y; Bs[lk + 6][lr] = b1.z; Bs[lk + 7][lr] = b1.w;
    __syncthreads();
    #pragma unroll
    for (int kk = 0; kk < 32; ++kk) {
      const float4 av = *(const float4*)&As[kk][ty * 4];
      const float4 bv = *(const float4*)&Bs[kk][tx * 4];
      const float ar[4] = {av.x, av.y, av.z, av.w};
      const float br[4] = {bv.x, bv.y, bv.z, bv.w};
      #pragma unroll
      for (int i = 0; i < 4; ++i)
        #pragma unroll
        for (int j = 0; j < 4; ++j)
          acc[i][j] = fmaf(ar[i], br[j], acc[i][j]);
    }
  }

  const float4 bias = *(const float4*)&bm[jbase + tx * 4];
  const float bi[4] = {bias.x, bias.y, bias.z, bias.w};
  #pragma unroll
  for (int i = 0; i < 4; ++i) {
    const int r = rbase + ty * 4 + i;
    float v[4];
    #pragma unroll
    for (int j = 0; j < 4; ++j) {
      v[j] = acc[i][j] + bi[j];
      if (mat & 1) v[j] = sigm(v[j]);   // mats 1 (erase) and 3 (g) are sigmoids
    }
    float4 o; o.x = v[0]; o.y = v[1]; o.z = v[2]; o.w = v[3];
    if (mat == 3) {
      *(float4*)&gout[(size_t)r * Dc + jbase + tx * 4] = o;   // g -> d_out (temp)
    } else {
      float* dst = ws + (mat == 0 ? OFF_KN : (mat == 1 ? OFF_E : OFF_A));
      const int t = r & 255, b = r >> 8;                      // r = b*T + t
      *(float4*)&dst[((size_t)t * Bc + b) * Dc + jbase + tx * 4] = o;
    }
  }
}

// ---------------------------------------------------------------------------
// K2: l2-normalize each of the T*B rows of k in place.
// ---------------------------------------------------------------------------
__global__ __launch_bounds__(256) void k_knorm(float* __restrict__ kn)
{
  const int row = blockIdx.x * 4 + (threadIdx.x >> 6);
  const int lane = threadIdx.x & 63;
  float* p = kn + (size_t)row * Dc;
  float4 v0 = *(const float4*)&p[lane * 4];
  float4 v1 = *(const float4*)&p[256 + lane * 4];
  float ss = v0.x*v0.x + v0.y*v0.y + v0.z*v0.z + v0.w*v0.w
           + v1.x*v1.x + v1.y*v1.y + v1.z*v1.z + v1.w*v1.w;
  #pragma unroll
  for (int off = 32; off >= 1; off >>= 1) ss += __shfl_xor(ss, off);
  const float inv = 1.0f / fmaxf(sqrtf(ss), 1e-12f);
  v0.x *= inv; v0.y *= inv; v0.z *= inv; v0.w *= inv;
  v1.x *= inv; v1.y *= inv; v1.z *= inv; v1.w *= inv;
  *(float4*)&p[lane * 4] = v0;
  *(float4*)&p[256 + lane * 4] = v1;
}

// ---------------------------------------------------------------------------
// K3: persistent recurrent kernel. 256 blocks x 256 threads, one device-wide
// barrier per step. Blocks 0..127 = W (mem update + LN + next-step sim),
// blocks 128..255 = R (read partials); blocks 128..135 additionally write the
// gated outputs one step behind.
// ---------------------------------------------------------------------------
DEV void gbar(unsigned* cnt, unsigned target)
{
  __threadfence();                       // release our writes device-wide
  __syncthreads();
  if (threadIdx.x == 0) {
    __hip_atomic_fetch_add(cnt, 1u, __ATOMIC_ACQ_REL, __HIP_MEMORY_SCOPE_AGENT);
    while (__hip_atomic_load(cnt, __ATOMIC_ACQUIRE, __HIP_MEMORY_SCOPE_AGENT) < target) {
      __builtin_amdgcn_s_sleep(2);
    }
  }
  __syncthreads();
  __threadfence();                       // acquire: drop stale cached lines
}

DEV void sim_phase(const float* __restrict__ knp, float* __restrict__ ewn,
                   float* __restrict__ denp, float (*xb)[516],
                   const float* invn_s, float* sred, int s0, int tid)
{
  const int r = tid >> 4, bp = tid & 15;
  const float* k0p = knp + (size_t)bp * Dc;
  const float* k1p = knp + (size_t)(bp + 16) * Dc;
  float acc0 = 0.f, acc1 = 0.f;
  #pragma unroll 4
  for (int dq = 0; dq < Dc / 4; ++dq) {
    const float4 y4 = *(const float4*)&xb[r][dq * 4];
    const float4 ka = *(const float4*)&k0p[dq * 4];
    const float4 kb = *(const float4*)&k1p[dq * 4];
    acc0 = fmaf(y4.x, ka.x, acc0); acc0 = fmaf(y4.y, ka.y, acc0);
    acc0 = fmaf(y4.z, ka.z, acc0); acc0 = fmaf(y4.w, ka.w, acc0);
    acc1 = fmaf(y4.x, kb.x, acc1); acc1 = fmaf(y4.y, kb.y, acc1);
    acc1 = fmaf(y4.z, kb.z, acc1); acc1 = fmaf(y4.w, kb.w, acc1);
  }
  const float iv = invn_s[r];
  const float e0 = __expf(acc0 * iv);
  const float e1 = __expf(acc1 * iv);
  ewn[(size_t)(s0 + r) * Bc + bp]      = e0;
  ewn[(size_t)(s0 + r) * Bc + bp + 16] = e1;
  if (tid < 32) sred[tid] = 0.f;
  __syncthreads();
  atomicAdd(&sred[bp], e0);
  atomicAdd(&sred[bp + 16], e1);
  __syncthreads();
  if (tid < 32) atomicAdd(&denp[tid], sred[tid]);
}

__global__ __launch_bounds__(256) void k_main(
    const float* __restrict__ cs,      // [B][T][D]
    const float* __restrict__ mem_in,  // [S][D]
    const float* __restrict__ gamma, const float* __restrict__ beta,
    float* __restrict__ ws, float* __restrict__ out)
{
  __shared__ float xbuf[16][516];
  __shared__ float wbuf[16][32];
  __shared__ float sred[32];
  __shared__ float mu_s[16], rs_s[16], invn_s[16];
  __shared__ float dinv_s[32];

  float* kn   = ws + OFF_KN;
  float* eptb = ws + OFF_E;
  float* aptb = ws + OFF_A;
  float* memb = ws + OFF_MEM;
  float* ewb  = ws + OFF_EW;
  float* rp   = ws + OFF_RP;
  float* den  = ws + OFF_DEN;
  unsigned* cnt = (unsigned*)(ws + OFF_CNT);

  const int bid = blockIdx.x, tid = threadIdx.x;
  unsigned bart = 0;
  const float inv32 = 1.0f / 32.0f;

  // ----- prologue: ew_0 / denom_0 from the input memory; copy mem -> buf0 -----
  if (bid < NW) {
    const int s0 = bid * ROWS;
    const int c0 = tid * 2;
    #pragma unroll
    for (int r = 0; r < ROWS; ++r) {
      const float2 m = *(const float2*)&mem_in[(size_t)(s0 + r) * Dc + c0];
      *(float2*)&xbuf[r][c0] = m;
      *(float2*)&memb[(size_t)(s0 + r) * Dc + c0] = m;
    }
    __syncthreads();
    {
      const int row = tid >> 4, li = tid & 15;
      float ss = 0.f;
      #pragma unroll
      for (int i = 0; i < 8; ++i) {
        const float4 v = *(const float4*)&xbuf[row][(li + i * 16) * 4];
        ss += v.x*v.x + v.y*v.y + v.z*v.z + v.w*v.w;
      }
      ss += __shfl_xor(ss, 8); ss += __shfl_xor(ss, 4);
      ss += __shfl_xor(ss, 2); ss += __shfl_xor(ss, 1);
      if (li == 0) invn_s[row] = 1.0f / fmaxf(sqrtf(ss), 1e-12f);
    }
    __syncthreads();
    sim_phase(kn, ewb, den, xbuf, invn_s, sred, s0, tid);
  }
  bart += NBLK; gbar(cnt, bart);

  // ----- main loop -----
  for (int t = 0; t <= Tc; ++t) {
    if (bid < NW) {
      if (t < Tc - 1) {
        const int s0 = bid * ROWS;
        const int c0 = tid * 2;
        const float* ewc = ewb + (size_t)(t & 1) * Sc * Bc;
        float*       ewn = ewb + (size_t)((t + 1) & 1) * Sc * Bc;
        const float* memc = memb + (size_t)(t & 1) * Sc * Dc;
        float*       memn = memb + (size_t)((t + 1) & 1) * Sc * Dc;

        if (tid < 32) dinv_s[tid] = 1.0f / den[(size_t)t * Bc + tid];
        __syncthreads();
        for (int idx = tid; idx < ROWS * 32; idx += 256) {
          const int r = idx >> 5, b = idx & 31;
          wbuf[r][b] = ewc[(size_t)(s0 + r) * Bc + b] * dinv_s[b];
        }
        __syncthreads();

        // rank-32 erase/add update, thread owns cols c0,c0+1 of all 16 rows
        float2 er[ROWS] = {}, ad[ROWS] = {};
        const float* ept = eptb + (size_t)t * Bc * Dc;
        const float* apt = aptb + (size_t)t * Bc * Dc;
        #pragma unroll 4
        for (int b = 0; b < 32; ++b) {
          const float2 ev = *(const float2*)&ept[(size_t)b * Dc + c0];
          const float2 av = *(const float2*)&apt[(size_t)b * Dc + c0];
          #pragma unroll
          for (int r = 0; r < ROWS; ++r) {
            const float wv = wbuf[r][b];
            er[r].x = fmaf(wv, ev.x, er[r].x); er[r].y = fmaf(wv, ev.y, er[r].y);
            ad[r].x = fmaf(wv, av.x, ad[r].x); ad[r].y = fmaf(wv, av.y, ad[r].y);
          }
        }
        float2 xr[ROWS];
        #pragma unroll
        for (int r = 0; r < ROWS; ++r) {
          const float2 m = *(const float2*)&memc[(size_t)(s0 + r) * Dc + c0];
          float2 x;
          x.x = m.x * (1.0f - er[r].x * inv32) + ad[r].x * inv32;
          x.y = m.y * (1.0f - er[r].y * inv32) + ad[r].y * inv32;
          xr[r] = x;
          *(float2*)&xbuf[r][c0] = x;
        }
        __syncthreads();
        // LN stats per row
        {
          const int row = tid >> 4, li = tid & 15;
          float s1 = 0.f, s2 = 0.f;
          #pragma unroll
          for (int i = 0; i < 8; ++i) {
            const float4 v = *(const float4*)&xbuf[row][(li + i * 16) * 4];
            s1 += v.x + v.y + v.z + v.w;
            s2 += v.x*v.x + v.y*v.y + v.z*v.z + v.w*v.w;
          }
          s1 += __shfl_xor(s1, 8); s2 += __shfl_xor(s2, 8);
          s1 += __shfl_xor(s1, 4); s2 += __shfl_xor(s2, 4);
          s1 += __shfl_xor(s1, 2); s2 += __shfl_xor(s2, 2);
          s1 += __shfl_xor(s1, 1); s2 += __shfl_xor(s2, 1);
          if (li == 0) {
            const float mu = s1 * (1.0f / 512.0f);
            const float var = s2 * (1.0f / 512.0f) - mu * mu;
            mu_s[row] = mu;
            rs_s[row] = rsqrtf(var + 1e-5f);
          }
        }
        __syncthreads();
        const float2 gm  = *(const float2*)&gamma[c0];
        const float2 bt2 = *(const float2*)&beta[c0];
        #pragma unroll
        for (int r = 0; r < ROWS; ++r) {
          const float mu = mu_s[r], rs = rs_s[r];
          float2 y;
          y.x = (xr[r].x - mu) * rs * gm.x + bt2.x;
          y.y = (xr[r].y - mu) * rs * gm.y + bt2.y;
          *(float2*)&xbuf[r][c0] = y;
          *(float2*)&memn[(size_t)(s0 + r) * Dc + c0] = y;
        }
        __syncthreads();
        // row l2 norms of new memory
        {
          const int row = tid >> 4, li = tid & 15;
          float ss = 0.f;
          #pragma unroll
          for (int i = 0; i < 8; ++i) {
            const float4 v = *(const float4*)&xbuf[row][(li + i * 16) * 4];
            ss += v.x*v.x + v.y*v.y + v.z*v.z + v.w*v.w;
          }
          ss += __shfl_xor(ss, 8); ss += __shfl_xor(ss, 4);
          ss += __shfl_xor(ss, 2); ss += __shfl_xor(ss, 1);
          if (li == 0) invn_s[row] = 1.0f / fmaxf(sqrtf(ss), 1e-12f);
        }
        __syncthreads();
        sim_phase(kn + (size_t)(t + 1) * Bc * Dc, ewn,
                  den + (size_t)(t + 1) * Bc, xbuf, invn_s, sred, s0, tid);
      }
    } else {
      const int rb = bid - NW;
      // O duty: gated output for step t-1
      if (rb < 8 && t >= 1) {
        const int t0 = t - 1;
        const float* rpc = rp + (size_t)(t0 & 1) * 16 * Bc * Dc;
        const int base = (rb * 256 + tid) * 8;
        const int b = base >> 9, d0 = base & 511;
        const float inv = 1.0f / den[(size_t)t0 * Bc + b];
        float r0[4] = {}, r1[4] = {};
        #pragma unroll
        for (int si = 0; si < 16; ++si) {
          const float* q = rpc + ((size_t)si * Bc + b) * Dc + d0;
          const float4 p0 = *(const float4*)&q[0];
          const float4 p1 = *(const float4*)&q[4];
          r0[0] += p0.x; r0[1] += p0.y; r0[2] += p0.z; r0[3] += p0.w;
          r1[0] += p1.x; r1[1] += p1.y; r1[2] += p1.z; r1[3] += p1.w;
        }
        const size_t oofs = ((size_t)b * Tc + t0) * Dc + d0;
        const float4 g0 = *(const float4*)&out[oofs];
        const float4 g1 = *(const float4*)&out[oofs + 4];
        const float4 c0v = *(const float4*)&cs[oofs];
        const float4 c1v = *(const float4*)&cs[oofs + 4];
        float4 o0, o1;
        o0.x = g0.x * c0v.x + (1.0f - g0.x) * (r0[0] * inv);
        o0.y = g0.y * c0v.y + (1.0f - g0.y) * (r0[1] * inv);
        o0.z = g0.z * c0v.z + (1.0f - g0.z) * (r0[2] * inv);
        o0.w = g0.w * c0v.w + (1.0f - g0.w) * (r0[3] * inv);
        o1.x = g1.x * c1v.x + (1.0f - g1.x) * (r1[0] * inv);
        o1.y = g1.y * c1v.y + (1.0f - g1.y) * (r1[1] * inv);
        o1.z = g1.z * c1v.z + (1.0f - g1.z) * (r1[2] * inv);
        o1.w = g1.w * c1v.w + (1.0f - g1.w) * (r1[3] * inv);
        *(float4*)&out[oofs] = o0;
        *(float4*)&out[oofs + 4] = o1;
      }
      // R: unnormalized read partials for step t
      if (t < Tc) {
        const int si = rb >> 3, dj = rb & 7;
        const int sB = si * 128;
        const float* ewc = ewb + (size_t)(t & 1) * Sc * Bc;
        const float* memc = memb + (size_t)(t & 1) * Sc * Dc;
        float* ewl = (float*)xbuf;
        for (int i = tid; i < 128 * 32; i += 256) ewl[i] = ewc[(size_t)sB * Bc + i];
        __syncthreads();
        const int b = tid >> 3, dg = tid & 7;
        const int cbase = dj * 64 + dg * 8;
        float a0[4] = {}, a1[4] = {};
        #pragma unroll 2
        for (int s = 0; s < 128; ++s) {
          const float wv = ewl[s * 32 + b];
          const float* mrow = memc + (size_t)(sB + s) * Dc + cbase;
          const float4 m0 = *(const float4*)&mrow[0];
          const float4 m1 = *(const float4*)&mrow[4];
          a0[0] = fmaf(wv, m0.x, a0[0]); a0[1] = fmaf(wv, m0.y, a0[1]);
          a0[2] = fmaf(wv, m0.z, a0[2]); a0[3] = fmaf(wv, m0.w, a0[3]);
          a1[0] = fmaf(wv, m1.x, a1[0]); a1[1] = fmaf(wv, m1.y, a1[1]);
          a1[2] = fmaf(wv, m1.z, a1[2]); a1[3] = fmaf(wv, m1.w, a1[3]);
        }
        float* dst = rp + (size_t)(t & 1) * 16 * Bc * Dc + ((size_t)si * Bc + b) * Dc + cbase;
        float4 w0, w1;
        w0.x = a0[0]; w0.y = a0[1]; w0.z = a0[2]; w0.w = a0[3];
        w1.x = a1[0]; w1.y = a1[1]; w1.z = a1[2]; w1.w = a1[3];
        *(float4*)&dst[0] = w0;
        *(float4*)&dst[4] = w1;
        __syncthreads();
      }
    }
    bart += NBLK; gbar(cnt, bart);
  }
}

// ---------------------------------------------------------------------------
extern "C" void kernel_launch(void* const* d_in, const int* in_sizes, int n_in,
                              void* d_out, int out_size, void* d_ws, size_t ws_size,
                              hipStream_t stream)
{
  const float* cs    = (const float*)d_in[0];
  const float* mem   = (const float*)d_in[1];
  const float* Wk    = (const float*)d_in[2];
  const float* bk    = (const float*)d_in[3];
  const float* We    = (const float*)d_in[4];
  const float* be    = (const float*)d_in[5];
  const float* Ww    = (const float*)d_in[6];
  const float* bw    = (const float*)d_in[7];
  const float* Wg    = (const float*)d_in[8];
  const float* bg    = (const float*)d_in[9];
  const float* gamma = (const float*)d_in[10];
  const float* beta  = (const float*)d_in[11];
  float* ws  = (float*)d_ws;
  float* out = (float*)d_out;

  // zero denominators + barrier counter (contiguous)
  hipMemsetAsync(ws + OFF_DEN, 0, ((size_t)Tc * Bc + 1) * sizeof(float), stream);

  hipLaunchKernelGGL(k_gemm, dim3(4096), dim3(256), 0, stream,
                     cs, Wk, bk, We, be, Ww, bw, Wg, bg, ws, out);
  hipLaunchKernelGGL(k_knorm, dim3(2048), dim3(256), 0, stream, ws + OFF_KN);
  hipLaunchKernelGGL(k_main, dim3(NBLK), dim3(256), 0, stream,
                     cs, mem, gamma, beta, ws, out);
}

// Round 2
// 10777.612 us; speedup vs baseline: 2.2109x; 2.2109x over previous
//
#include <hip/hip_runtime.h>

#define DEV __device__ __forceinline__

namespace {
constexpr int Bc = 32;
constexpr int Tc = 256;
constexpr int Dc = 512;
constexpr int Sc = 2048;
constexpr int NBLK = 256;
constexpr int NW   = 128;          // writer blocks
constexpr int ROWS = Sc / NW;      // 16 memory rows per W block

// workspace layout (float offsets)
constexpr size_t OFF_KN  = 0;                                   // [T][B][D] normalized k
constexpr size_t OFF_E   = OFF_KN  + (size_t)Tc * Bc * Dc;      // [T][B][D] sigmoid(erase)
constexpr size_t OFF_A   = OFF_E   + (size_t)Tc * Bc * Dc;      // [T][B][D] add
constexpr size_t OFF_MEM = OFF_A   + (size_t)Tc * Bc * Dc;      // [2][S][D] memory ping-pong
constexpr size_t OFF_EW  = OFF_MEM + (size_t)2 * Sc * Dc;       // [2][S][B] exp(sim)
constexpr size_t OFF_RP  = OFF_EW  + (size_t)2 * Sc * Bc;       // [2][16][B][D] read partials
constexpr size_t OFF_DEN = OFF_RP  + (size_t)2 * 16 * Bc * Dc;  // [T][B] softmax denominators
}

DEV float sigm(float x) { return 1.0f / (1.0f + __expf(-x)); }

// ---------------------------------------------------------------------------
// K1: C[r][j] = sum_d A[r][d] * W[j][d] + bias[j], for 4 weight matrices.
// ---------------------------------------------------------------------------
__global__ __launch_bounds__(256) void k_gemm(
    const float* __restrict__ A,
    const float* __restrict__ Wk, const float* __restrict__ bk,
    const float* __restrict__ We, const float* __restrict__ be,
    const float* __restrict__ Ww, const float* __restrict__ bw,
    const float* __restrict__ Wg, const float* __restrict__ bg,
    float* __restrict__ ws, float* __restrict__ gout)
{
  __shared__ float As[32][68];
  __shared__ float Bs[32][68];

  const int bid = blockIdx.x;
  const int mat = bid >> 10;
  const int rem = bid & 1023;
  const int rt = rem >> 3, jt = rem & 7;
  const int rbase = rt * 64, jbase = jt * 64;

  const float* Wm; const float* bm;
  if      (mat == 0) { Wm = Wk; bm = bk; }
  else if (mat == 1) { Wm = We; bm = be; }
  else if (mat == 2) { Wm = Ww; bm = bw; }
  else               { Wm = Wg; bm = bg; }

  const int tid = threadIdx.x;
  const int lr = tid >> 2;
  const int lk = (tid & 3) * 8;
  const int ty = tid >> 4, tx = tid & 15;

  float acc[4][4] = {};

  for (int k0 = 0; k0 < Dc; k0 += 32) {
    const float4 a0 = *(const float4*)&A [(size_t)(rbase + lr) * Dc + k0 + lk];
    const float4 a1 = *(const float4*)&A [(size_t)(rbase + lr) * Dc + k0 + lk + 4];
    const float4 b0 = *(const float4*)&Wm[(size_t)(jbase + lr) * Dc + k0 + lk];
    const float4 b1 = *(const float4*)&Wm[(size_t)(jbase + lr) * Dc + k0 + lk + 4];
    __syncthreads();
    As[lk + 0][lr] = a0.x; As[lk + 1][lr] = a0.y; As[lk + 2][lr] = a0.z; As[lk + 3][lr] = a0.w;
    As[lk + 4][lr] = a1.x; As[lk + 5][lr] = a1.y; As[lk + 6][lr] = a1.z; As[lk + 7][lr] = a1.w;
    Bs[lk + 0][lr] = b0.x; Bs[lk + 1][lr] = b0.y; Bs[lk + 2][lr] = b0.z; Bs[lk + 3][lr] = b0.w;
    Bs[lk + 4][lr] = b1.x; Bs[lk + 5][lr] = b1.y; Bs[lk + 6][lr] = b1.z; Bs[lk + 7][lr] = b1.w;
    __syncthreads();
    #pragma unroll
    for (int kk = 0; kk < 32; ++kk) {
      const float4 av = *(const float4*)&As[kk][ty * 4];
      const float4 bv = *(const float4*)&Bs[kk][tx * 4];
      const float ar[4] = {av.x, av.y, av.z, av.w};
      const float br[4] = {bv.x, bv.y, bv.z, bv.w};
      #pragma unroll
      for (int i = 0; i < 4; ++i)
        #pragma unroll
        for (int j = 0; j < 4; ++j)
          acc[i][j] = fmaf(ar[i], br[j], acc[i][j]);
    }
  }

  const float4 bias = *(const float4*)&bm[jbase + tx * 4];
  const float bi[4] = {bias.x, bias.y, bias.z, bias.w};
  #pragma unroll
  for (int i = 0; i < 4; ++i) {
    const int r = rbase + ty * 4 + i;
    float v[4];
    #pragma unroll
    for (int j = 0; j < 4; ++j) {
      v[j] = acc[i][j] + bi[j];
      if (mat & 1) v[j] = sigm(v[j]);
    }
    float4 o; o.x = v[0]; o.y = v[1]; o.z = v[2]; o.w = v[3];
    if (mat == 3) {
      *(float4*)&gout[(size_t)r * Dc + jbase + tx * 4] = o;   // g -> d_out (temp)
    } else {
      float* dst = ws + (mat == 0 ? OFF_KN : (mat == 1 ? OFF_E : OFF_A));
      const int t = r & 255, b = r >> 8;                      // r = b*T + t
      *(float4*)&dst[((size_t)t * Bc + b) * Dc + jbase + tx * 4] = o;
    }
  }
}

// ---------------------------------------------------------------------------
// K2: l2-normalize each of the T*B rows of k in place.
// ---------------------------------------------------------------------------
__global__ __launch_bounds__(256) void k_knorm(float* __restrict__ kn)
{
  const int row = blockIdx.x * 4 + (threadIdx.x >> 6);
  const int lane = threadIdx.x & 63;
  float* p = kn + (size_t)row * Dc;
  float4 v0 = *(const float4*)&p[lane * 4];
  float4 v1 = *(const float4*)&p[256 + lane * 4];
  float ss = v0.x*v0.x + v0.y*v0.y + v0.z*v0.z + v0.w*v0.w
           + v1.x*v1.x + v1.y*v1.y + v1.z*v1.z + v1.w*v1.w;
  #pragma unroll
  for (int off = 32; off >= 1; off >>= 1) ss += __shfl_xor(ss, off);
  const float inv = 1.0f / fmaxf(sqrtf(ss), 1e-12f);
  v0.x *= inv; v0.y *= inv; v0.z *= inv; v0.w *= inv;
  v1.x *= inv; v1.y *= inv; v1.z *= inv; v1.w *= inv;
  *(float4*)&p[lane * 4] = v0;
  *(float4*)&p[256 + lane * 4] = v1;
}

// ---------------------------------------------------------------------------
// sim phase: xbuf holds 16 freshly written memory rows (unnormalized dot is
// scaled by the row inv-norm afterwards). Writes ew rows, atomicAdds denom.
// ---------------------------------------------------------------------------
DEV void sim_phase(const float* __restrict__ knp, float* __restrict__ ewn,
                   float* __restrict__ denp, float (*xb)[516],
                   const float* invn_s, float* sred, int s0, int tid)
{
  const int r = tid >> 4, bp = tid & 15;
  const float* k0p = knp + (size_t)bp * Dc;
  const float* k1p = knp + (size_t)(bp + 16) * Dc;
  float acc0 = 0.f, acc1 = 0.f;
  #pragma unroll 4
  for (int dq = 0; dq < Dc / 4; ++dq) {
    const float4 y4 = *(const float4*)&xb[r][dq * 4];
    const float4 ka = *(const float4*)&k0p[dq * 4];
    const float4 kb = *(const float4*)&k1p[dq * 4];
    acc0 = fmaf(y4.x, ka.x, acc0); acc0 = fmaf(y4.y, ka.y, acc0);
    acc0 = fmaf(y4.z, ka.z, acc0); acc0 = fmaf(y4.w, ka.w, acc0);
    acc1 = fmaf(y4.x, kb.x, acc1); acc1 = fmaf(y4.y, kb.y, acc1);
    acc1 = fmaf(y4.z, kb.z, acc1); acc1 = fmaf(y4.w, kb.w, acc1);
  }
  const float iv = invn_s[r];
  const float e0 = __expf(acc0 * iv);
  const float e1 = __expf(acc1 * iv);
  ewn[(size_t)(s0 + r) * Bc + bp]      = e0;
  ewn[(size_t)(s0 + r) * Bc + bp + 16] = e1;
  if (tid < 32) sred[tid] = 0.f;
  __syncthreads();
  atomicAdd(&sred[bp], e0);
  atomicAdd(&sred[bp + 16], e1);
  __syncthreads();
  if (tid < 32) atomicAdd(&denp[tid], sred[tid]);
}

// ---------------------------------------------------------------------------
// Prologue: copy mem -> buf0, compute ew_0 / den_0. Grid = 128 blocks.
// ---------------------------------------------------------------------------
__global__ __launch_bounds__(256) void k_prologue(
    const float* __restrict__ mem_in, float* __restrict__ ws)
{
  __shared__ float xbuf[16][516];
  __shared__ float sred[32];
  __shared__ float invn_s[16];

  float* kn   = ws + OFF_KN;
  float* memb = ws + OFF_MEM;
  float* ewb  = ws + OFF_EW;
  float* den  = ws + OFF_DEN;

  const int bid = blockIdx.x, tid = threadIdx.x;
  const int s0 = bid * ROWS;
  const int c0 = tid * 2;
  #pragma unroll
  for (int r = 0; r < ROWS; ++r) {
    const float2 m = *(const float2*)&mem_in[(size_t)(s0 + r) * Dc + c0];
    *(float2*)&xbuf[r][c0] = m;
    *(float2*)&memb[(size_t)(s0 + r) * Dc + c0] = m;
  }
  __syncthreads();
  {
    const int row = tid >> 4, li = tid & 15;
    float ss = 0.f;
    #pragma unroll
    for (int i = 0; i < 8; ++i) {
      const float4 v = *(const float4*)&xbuf[row][(li + i * 16) * 4];
      ss += v.x*v.x + v.y*v.y + v.z*v.z + v.w*v.w;
    }
    ss += __shfl_xor(ss, 8); ss += __shfl_xor(ss, 4);
    ss += __shfl_xor(ss, 2); ss += __shfl_xor(ss, 1);
    if (li == 0) invn_s[row] = 1.0f / fmaxf(sqrtf(ss), 1e-12f);
  }
  __syncthreads();
  sim_phase(kn, ewb, den, xbuf, invn_s, sred, s0, tid);
}

// ---------------------------------------------------------------------------
// k_step(t): one timestep. Kernel boundaries provide device-wide ordering.
//  blocks 0..127   (W): mem_t -> mem_{t+1} (erase/add + LN), then ew_{t+1},
//                       den_{t+1} for its 16 rows           [active t < Tc-1]
//  blocks 128..255 (R): rp_t = ew_t @ mem_t slice            [active t < Tc]
//  blocks 128..135 (O): out_{t-1} from rp_{t-1}/den_{t-1}    [active t >= 1]
// ---------------------------------------------------------------------------
__global__ __launch_bounds__(256) void k_step(
    int t,
    const float* __restrict__ cs,
    const float* __restrict__ gamma, const float* __restrict__ beta,
    float* __restrict__ ws, float* __restrict__ out)
{
  __shared__ float xbuf[16][516];
  __shared__ float wbuf[16][32];
  __shared__ float sred[32];
  __shared__ float mu_s[16], rs_s[16], invn_s[16];
  __shared__ float dinv_s[32];

  float* kn   = ws + OFF_KN;
  float* eptb = ws + OFF_E;
  float* aptb = ws + OFF_A;
  float* memb = ws + OFF_MEM;
  float* ewb  = ws + OFF_EW;
  float* rp   = ws + OFF_RP;
  float* den  = ws + OFF_DEN;

  const int bid = blockIdx.x, tid = threadIdx.x;
  const float inv32 = 1.0f / 32.0f;

  if (bid < NW) {
    if (t < Tc - 1) {
      const int s0 = bid * ROWS;
      const int c0 = tid * 2;
      const float* ewc = ewb + (size_t)(t & 1) * Sc * Bc;
      float*       ewn = ewb + (size_t)((t + 1) & 1) * Sc * Bc;
      const float* memc = memb + (size_t)(t & 1) * Sc * Dc;
      float*       memn = memb + (size_t)((t + 1) & 1) * Sc * Dc;

      if (tid < 32) dinv_s[tid] = 1.0f / den[(size_t)t * Bc + tid];
      __syncthreads();
      for (int idx = tid; idx < ROWS * 32; idx += 256) {
        const int r = idx >> 5, b = idx & 31;
        wbuf[r][b] = ewc[(size_t)(s0 + r) * Bc + b] * dinv_s[b];
      }
      __syncthreads();

      // rank-32 erase/add update
      float2 er[ROWS] = {}, ad[ROWS] = {};
      const float* ept = eptb + (size_t)t * Bc * Dc;
      const float* apt = aptb + (size_t)t * Bc * Dc;
      #pragma unroll 4
      for (int b = 0; b < 32; ++b) {
        const float2 ev = *(const float2*)&ept[(size_t)b * Dc + c0];
        const float2 av = *(const float2*)&apt[(size_t)b * Dc + c0];
        #pragma unroll
        for (int r = 0; r < ROWS; ++r) {
          const float wv = wbuf[r][b];
          er[r].x = fmaf(wv, ev.x, er[r].x); er[r].y = fmaf(wv, ev.y, er[r].y);
          ad[r].x = fmaf(wv, av.x, ad[r].x); ad[r].y = fmaf(wv, av.y, ad[r].y);
        }
      }
      float2 xr[ROWS];
      #pragma unroll
      for (int r = 0; r < ROWS; ++r) {
        const float2 m = *(const float2*)&memc[(size_t)(s0 + r) * Dc + c0];
        float2 x;
        x.x = m.x * (1.0f - er[r].x * inv32) + ad[r].x * inv32;
        x.y = m.y * (1.0f - er[r].y * inv32) + ad[r].y * inv32;
        xr[r] = x;
        *(float2*)&xbuf[r][c0] = x;
      }
      __syncthreads();
      // LN stats per row
      {
        const int row = tid >> 4, li = tid & 15;
        float s1 = 0.f, s2 = 0.f;
        #pragma unroll
        for (int i = 0; i < 8; ++i) {
          const float4 v = *(const float4*)&xbuf[row][(li + i * 16) * 4];
          s1 += v.x + v.y + v.z + v.w;
          s2 += v.x*v.x + v.y*v.y + v.z*v.z + v.w*v.w;
        }
        s1 += __shfl_xor(s1, 8); s2 += __shfl_xor(s2, 8);
        s1 += __shfl_xor(s1, 4); s2 += __shfl_xor(s2, 4);
        s1 += __shfl_xor(s1, 2); s2 += __shfl_xor(s2, 2);
        s1 += __shfl_xor(s1, 1); s2 += __shfl_xor(s2, 1);
        if (li == 0) {
          const float mu = s1 * (1.0f / 512.0f);
          const float var = s2 * (1.0f / 512.0f) - mu * mu;
          mu_s[row] = mu;
          rs_s[row] = rsqrtf(var + 1e-5f);
        }
      }
      __syncthreads();
      const float2 gm  = *(const float2*)&gamma[c0];
      const float2 bt2 = *(const float2*)&beta[c0];
      #pragma unroll
      for (int r = 0; r < ROWS; ++r) {
        const float mu = mu_s[r], rs = rs_s[r];
        float2 y;
        y.x = (xr[r].x - mu) * rs * gm.x + bt2.x;
        y.y = (xr[r].y - mu) * rs * gm.y + bt2.y;
        *(float2*)&xbuf[r][c0] = y;
        *(float2*)&memn[(size_t)(s0 + r) * Dc + c0] = y;
      }
      __syncthreads();
      // row l2 norms of new memory
      {
        const int row = tid >> 4, li = tid & 15;
        float ss = 0.f;
        #pragma unroll
        for (int i = 0; i < 8; ++i) {
          const float4 v = *(const float4*)&xbuf[row][(li + i * 16) * 4];
          ss += v.x*v.x + v.y*v.y + v.z*v.z + v.w*v.w;
        }
        ss += __shfl_xor(ss, 8); ss += __shfl_xor(ss, 4);
        ss += __shfl_xor(ss, 2); ss += __shfl_xor(ss, 1);
        if (li == 0) invn_s[row] = 1.0f / fmaxf(sqrtf(ss), 1e-12f);
      }
      __syncthreads();
      sim_phase(kn + (size_t)(t + 1) * Bc * Dc, ewn,
                den + (size_t)(t + 1) * Bc, xbuf, invn_s, sred, s0, tid);
    }
  } else {
    const int rb = bid - NW;
    // O duty: gated output for step t-1
    if (rb < 8 && t >= 1) {
      const int t0 = t - 1;
      const float* rpc = rp + (size_t)(t0 & 1) * 16 * Bc * Dc;
      const int base = (rb * 256 + tid) * 8;
      const int b = base >> 9, d0 = base & 511;
      const float inv = 1.0f / den[(size_t)t0 * Bc + b];
      float r0[4] = {}, r1[4] = {};
      #pragma unroll
      for (int si = 0; si < 16; ++si) {
        const float* q = rpc + ((size_t)si * Bc + b) * Dc + d0;
        const float4 p0 = *(const float4*)&q[0];
        const float4 p1 = *(const float4*)&q[4];
        r0[0] += p0.x; r0[1] += p0.y; r0[2] += p0.z; r0[3] += p0.w;
        r1[0] += p1.x; r1[1] += p1.y; r1[2] += p1.z; r1[3] += p1.w;
      }
      const size_t oofs = ((size_t)b * Tc + t0) * Dc + d0;
      const float4 g0 = *(const float4*)&out[oofs];
      const float4 g1 = *(const float4*)&out[oofs + 4];
      const float4 c0v = *(const float4*)&cs[oofs];
      const float4 c1v = *(const float4*)&cs[oofs + 4];
      float4 o0, o1;
      o0.x = g0.x * c0v.x + (1.0f - g0.x) * (r0[0] * inv);
      o0.y = g0.y * c0v.y + (1.0f - g0.y) * (r0[1] * inv);
      o0.z = g0.z * c0v.z + (1.0f - g0.z) * (r0[2] * inv);
      o0.w = g0.w * c0v.w + (1.0f - g0.w) * (r0[3] * inv);
      o1.x = g1.x * c1v.x + (1.0f - g1.x) * (r1[0] * inv);
      o1.y = g1.y * c1v.y + (1.0f - g1.y) * (r1[1] * inv);
      o1.z = g1.z * c1v.z + (1.0f - g1.z) * (r1[2] * inv);
      o1.w = g1.w * c1v.w + (1.0f - g1.w) * (r1[3] * inv);
      *(float4*)&out[oofs] = o0;
      *(float4*)&out[oofs + 4] = o1;
    }
    // R duty: unnormalized read partials for step t
    if (t < Tc) {
      const int si = rb >> 3, dj = rb & 7;
      const int sB = si * 128;
      const float* ewc = ewb + (size_t)(t & 1) * Sc * Bc;
      const float* memc = memb + (size_t)(t & 1) * Sc * Dc;
      float* ewl = (float*)xbuf;
      for (int i = tid; i < 128 * 32; i += 256) ewl[i] = ewc[(size_t)sB * Bc + i];
      __syncthreads();
      const int b = tid >> 3, dg = tid & 7;
      const int cbase = dj * 64 + dg * 8;
      float a0[4] = {}, a1[4] = {};
      #pragma unroll 2
      for (int s = 0; s < 128; ++s) {
        const float wv = ewl[s * 32 + b];
        const float* mrow = memc + (size_t)(sB + s) * Dc + cbase;
        const float4 m0 = *(const float4*)&mrow[0];
        const float4 m1 = *(const float4*)&mrow[4];
        a0[0] = fmaf(wv, m0.x, a0[0]); a0[1] = fmaf(wv, m0.y, a0[1]);
        a0[2] = fmaf(wv, m0.z, a0[2]); a0[3] = fmaf(wv, m0.w, a0[3]);
        a1[0] = fmaf(wv, m1.x, a1[0]); a1[1] = fmaf(wv, m1.y, a1[1]);
        a1[2] = fmaf(wv, m1.z, a1[2]); a1[3] = fmaf(wv, m1.w, a1[3]);
      }
      float* dst = rp + (size_t)(t & 1) * 16 * Bc * Dc + ((size_t)si * Bc + b) * Dc + cbase;
      float4 w0, w1;
      w0.x = a0[0]; w0.y = a0[1]; w0.z = a0[2]; w0.w = a0[3];
      w1.x = a1[0]; w1.y = a1[1]; w1.z = a1[2]; w1.w = a1[3];
      *(float4*)&dst[0] = w0;
      *(float4*)&dst[4] = w1;
    }
  }
}

// ---------------------------------------------------------------------------
extern "C" void kernel_launch(void* const* d_in, const int* in_sizes, int n_in,
                              void* d_out, int out_size, void* d_ws, size_t ws_size,
                              hipStream_t stream)
{
  const float* cs    = (const float*)d_in[0];
  const float* mem   = (const float*)d_in[1];
  const float* Wk    = (const float*)d_in[2];
  const float* bk    = (const float*)d_in[3];
  const float* We    = (const float*)d_in[4];
  const float* be    = (const float*)d_in[5];
  const float* Ww    = (const float*)d_in[6];
  const float* bw    = (const float*)d_in[7];
  const float* Wg    = (const float*)d_in[8];
  const float* bg    = (const float*)d_in[9];
  const float* gamma = (const float*)d_in[10];
  const float* beta  = (const float*)d_in[11];
  float* ws  = (float*)d_ws;
  float* out = (float*)d_out;

  // zero softmax denominators (accumulated by device atomics each call)
  hipMemsetAsync(ws + OFF_DEN, 0, (size_t)Tc * Bc * sizeof(float), stream);

  hipLaunchKernelGGL(k_gemm, dim3(4096), dim3(256), 0, stream,
                     cs, Wk, bk, We, be, Ww, bw, Wg, bg, ws, out);
  hipLaunchKernelGGL(k_knorm, dim3(2048), dim3(256), 0, stream, ws + OFF_KN);
  hipLaunchKernelGGL(k_prologue, dim3(NW), dim3(256), 0, stream, mem, ws);

  for (int t = 0; t <= Tc; ++t) {
    hipLaunchKernelGGL(k_step, dim3(NBLK), dim3(256), 0, stream,
                       t, cs, gamma, beta, ws, out);
  }
}